// Round 1
// baseline (147.297 us; speedup 1.0000x reference)
//
#include <hip/hip_runtime.h>

// SelfMixing: CG tensor-product self-coupling, diagonal in channel.
// V2: LDS-staged I/O. All HBM traffic is float4 (16B/lane) — the previous
// version issued scalar dword loads/stores (strides 3/5/7 per lane), which
// caps streaming BW well below the float4 ceiling. Rows are staged through
// LDS; the scattered per-channel accesses hit LDS (strides 3/5/7 are coprime
// with 32 banks -> conflict-free). Thread classes are remapped so each wave
// is class-uniform (waves 0-1: ch 0..31 all-l, wave 2: ch 32..47 l0/l1,
// wave 3: ch 48..63 l0-only) — no intra-wave divergence.

namespace cgc {

struct cplx { double re, im; };
constexpr cplx cmul(cplx a, cplx b){ return {a.re*b.re - a.im*b.im, a.re*b.im + a.im*b.re}; }

constexpr double cfact(int n){ double r = 1.0; for (int i = 2; i <= n; ++i) r *= i; return r; }
constexpr double cabsd(double x){ return x < 0 ? -x : x; }

constexpr double csqrtd(double x){
  if (x <= 0.0) return 0.0;
  double g = x > 1.0 ? x : 1.0;
  for (int i = 0; i < 48; ++i) g = 0.5*(g + x/g);
  return g;
}

constexpr double SQRT2 = csqrtd(2.0);

constexpr double cg_complex(int l1,int m1,int l2,int m2,int l3,int m3){
  if (m1 + m2 != m3) return 0.0;
  int lo = l1 > l2 ? l1 - l2 : l2 - l1;
  if (l3 < lo || l3 > l1 + l2) return 0.0;
  double pre = csqrtd((2*l3+1) * cfact(l1+l2-l3)*cfact(l1-l2+l3)*cfact(-l1+l2+l3)/cfact(l1+l2+l3+1));
  pre *= csqrtd(cfact(l1+m1)*cfact(l1-m1)*cfact(l2+m2)*cfact(l2-m2)*cfact(l3+m3)*cfact(l3-m3));
  int kmin = 0;
  if (l2-l3-m1 > kmin) kmin = l2-l3-m1;
  if (l1-l3+m2 > kmin) kmin = l1-l3+m2;
  int kmax = l1+l2-l3;
  if (l1-m1 < kmax) kmax = l1-m1;
  if (l2+m2 < kmax) kmax = l2+m2;
  double s = 0.0;
  for (int k = kmin; k <= kmax; ++k){
    double d = cfact(k)*cfact(l1+l2-l3-k)*cfact(l1-m1-k)*cfact(l2+m2-k)
             * cfact(l3-l2+m1+k)*cfact(l3-l1-m2+k);
    s += ((k & 1) ? -1.0 : 1.0) / d;
  }
  return pre * s;
}

// U[r][c]: rows = real m' (r = m'+l), cols = complex m (c = m+l)
constexpr cplx Uent(int l, int r, int c){
  int m = r - l;
  if (m > 0){
    if (c ==  m + l) return { ((m & 1) ? -1.0 : 1.0)/SQRT2, 0.0 };
    if (c == -m + l) return { 1.0/SQRT2, 0.0 };
    return {0.0, 0.0};
  } else if (m == 0){
    if (c == l) return {1.0, 0.0};
    return {0.0, 0.0};
  } else {
    int ma = -m;
    if (c ==  m + l) return { 0.0, 1.0/SQRT2 };                       // 1j/sqrt2
    if (c == -m + l) return { 0.0, -(((ma & 1) ? -1.0 : 1.0))/SQRT2 };// -1j*(-1)^m/sqrt2
    return {0.0, 0.0};
  }
}

template<int L1,int L2,int L3>
struct CGData { float w[(2*L1+1)*(2*L2+1)*(2*L3+1)]; };

template<int L1,int L2,int L3>
constexpr CGData<L1,L2,L3> make_cg(){
  constexpr int D1 = 2*L1+1, D2 = 2*L2+1, D3 = 2*L3+1;
  cplx U1[D1*D1] = {}; cplx U2[D2*D2] = {}; cplx U3c[D3*D3] = {};
  for (int r = 0; r < D1; ++r) for (int c = 0; c < D1; ++c) U1[r*D1+c] = Uent(L1, r, c);
  for (int r = 0; r < D2; ++r) for (int c = 0; c < D2; ++c) U2[r*D2+c] = Uent(L2, r, c);
  for (int r = 0; r < D3; ++r) for (int c = 0; c < D3; ++c){
    cplx u = Uent(L3, r, c); u.im = -u.im; U3c[r*D3+c] = u;
  }
  double Cc[D1*D2*D3] = {};
  for (int m1 = -L1; m1 <= L1; ++m1)
    for (int m2 = -L2; m2 <= L2; ++m2){
      int m3 = m1 + m2;
      if (m3 < -L3 || m3 > L3) continue;
      Cc[((m1+L1)*D2 + (m2+L2))*D3 + (m3+L3)] = cg_complex(L1,m1,L2,m2,L3,m3);
    }
  double re[D1*D2*D3] = {}; double im[D1*D2*D3] = {};
  for (int a = 0; a < D1; ++a)
    for (int b = 0; b < D2; ++b)
      for (int c = 0; c < D3; ++c){
        double sre = 0.0, sim = 0.0;
        for (int m = 0; m < D1; ++m)
          for (int n = 0; n < D2; ++n){
            int o = m + n - L1 - L2 + L3;   // only nonzero Cc slice
            if (o < 0 || o >= D3) continue;
            double cc = Cc[(m*D2+n)*D3 + o];
            if (cc == 0.0) continue;
            cplx p = cmul(cmul(U1[a*D1+m], U2[b*D2+n]), U3c[c*D3+o]);
            sre += p.re * cc; sim += p.im * cc;
          }
        re[(a*D2+b)*D3+c] = sre; im[(a*D2+b)*D3+c] = sim;
      }
  double mre = 0.0, mim = 0.0;
  for (int k = 0; k < D1*D2*D3; ++k){
    if (cabsd(re[k]) > mre) mre = cabsd(re[k]);
    if (cabsd(im[k]) > mim) mim = cabsd(im[k]);
  }
  CGData<L1,L2,L3> outv{};
  for (int k = 0; k < D1*D2*D3; ++k){
    double v = (mim > mre) ? im[k] : re[k];
    outv.w[k] = (cabsd(v) < 1e-10) ? 0.0f : (float)v;
  }
  return outv;
}

} // namespace cgc

template<int L1,int L2,int L3>
__device__ __forceinline__ void tp_path(const float* xa, const float* xb, float cmix, float* acc){
  constexpr cgc::CGData<L1,L2,L3> cg = cgc::make_cg<L1,L2,L3>();
  constexpr int D1 = 2*L1+1, D2 = 2*L2+1, D3 = 2*L3+1;
  #pragma unroll
  for (int a = 0; a < D1; ++a){
    #pragma unroll
    for (int b = 0; b < D2; ++b){
      const float pr = xa[a] * xb[b];
      #pragma unroll
      for (int m = 0; m < D3; ++m){
        const float W = cg.w[(a*D2+b)*D3 + m];
        if (W != 0.0f) acc[m] += (cmix * W) * pr;   // folded at compile time; zeros DCE'd
      }
    }
  }
}

// Layout constants (match reference):
// OFF_IN  = [0, 64, 208, 368]; OFF_OUT = [0, 64, 208, 448, 672]
// mix bases per path order:
//  (0,0,0):0 (0,1,1):64 (0,2,2):112 (1,0,1):144 (1,1,0):192 (1,1,1):240 (1,1,2):288
//  (1,2,1):336 (1,2,2):368 (1,2,3):400 (2,0,2):432 (2,1,1):464 (2,1,2):496 (2,1,3):528
//  (2,2,0):560 (2,2,1):592 (2,2,2):624 (2,2,3):656
// keep chan: l0 -> i, l1 -> 64+i, l2 -> 112+i

#define ROWS_PER_BLOCK 4

__global__ __launch_bounds__(256) void selfmix_kernel(
    const float* __restrict__ x, const float* __restrict__ keep,
    const float* __restrict__ mix, float* __restrict__ out, int n)
{
  __shared__ __align__(16) float xs[ROWS_PER_BLOCK * 368];   //  5888 B
  __shared__ __align__(16) float os[ROWS_PER_BLOCK * 672];   // 10752 B

  const int t = threadIdx.x;
  const long long blk  = blockIdx.x;
  const long long row0 = blk * ROWS_PER_BLOCK;

  // ---- Phase 1: vectorized global -> LDS load of 4 rows (368 float4) ----
  {
    const long long nf4_in   = (long long)n * 92;          // total float4 in x
    const long long base_in  = blk * (ROWS_PER_BLOCK * 92); // = blk*368
    const float4* __restrict__ src = (const float4*)x;
    float4* dst = (float4*)xs;
    if (base_in + t < nf4_in)               dst[t]       = src[base_in + t];
    if (t < 112 && base_in + 256 + t < nf4_in) dst[256+t] = src[base_in + 256 + t];
  }
  __syncthreads();

  // ---- Phase 2: compute (classes wave-uniform) ----
  // wave 0,1: t=0..127   -> class A: row = t>>5,        i = t&31        (ch 0..31, all l)
  // wave 2  : t=128..191 -> class B: row = (t-128)>>4,  i = 32+(t&15)   (ch 32..47, l0+l1)
  // wave 3  : t=192..255 -> class C: row = (t-192)>>4,  i = 48+(t&15)   (ch 48..63, l0)
  if (t < 128){
    const int rowL = t >> 5;
    const int i    = t & 31;
    if (row0 + rowL < n){
      const float* xr = xs + rowL*368;
      float*     orow = os + rowL*672;
      float s = xr[i];
      float p[3], d[5];
      #pragma unroll
      for (int k = 0; k < 3; ++k) p[k] = xr[64 + i*3 + k];
      #pragma unroll
      for (int k = 0; k < 5; ++k) d[k] = xr[208 + i*5 + k];

      float o0 = 0.f;
      float o1[3] = {0.f,0.f,0.f};
      float o2[5] = {0.f,0.f,0.f,0.f,0.f};
      float o3[7] = {0.f,0.f,0.f,0.f,0.f,0.f,0.f};

      tp_path<0,0,0>(&s,&s, 0.5f*mix[  0+i], &o0);
      tp_path<0,1,1>(&s, p, 0.5f*mix[ 64+i],  o1);
      tp_path<0,2,2>(&s, d, 0.5f*mix[112+i],  o2);
      tp_path<1,0,1>( p,&s, 0.5f*mix[144+i],  o1);
      tp_path<1,1,0>( p, p, 0.5f*mix[192+i], &o0);
      tp_path<1,1,1>( p, p, 0.5f*mix[240+i],  o1);
      tp_path<1,1,2>( p, p, 0.5f*mix[288+i],  o2);
      tp_path<1,2,1>( p, d, 0.5f*mix[336+i],  o1);
      tp_path<1,2,2>( p, d, 0.5f*mix[368+i],  o2);
      tp_path<1,2,3>( p, d, 0.5f*mix[400+i],  o3);
      tp_path<2,0,2>( d,&s, 0.5f*mix[432+i],  o2);
      tp_path<2,1,1>( d, p, 0.5f*mix[464+i],  o1);
      tp_path<2,1,2>( d, p, 0.5f*mix[496+i],  o2);
      tp_path<2,1,3>( d, p, 0.5f*mix[528+i],  o3);
      tp_path<2,2,0>( d, d, 0.5f*mix[560+i], &o0);
      tp_path<2,2,1>( d, d, 0.5f*mix[592+i],  o1);
      tp_path<2,2,2>( d, d, 0.5f*mix[624+i],  o2);
      tp_path<2,2,3>( d, d, 0.5f*mix[656+i],  o3);

      // keep path
      o0 += keep[i] * s;
      const float k1 = keep[64+i], k2 = keep[112+i];
      #pragma unroll
      for (int k = 0; k < 3; ++k) o1[k] += k1 * p[k];
      #pragma unroll
      for (int k = 0; k < 5; ++k) o2[k] += k2 * d[k];

      orow[i] = o0;
      #pragma unroll
      for (int k = 0; k < 3; ++k) orow[ 64 + i*3 + k] = o1[k];
      #pragma unroll
      for (int k = 0; k < 5; ++k) orow[208 + i*5 + k] = o2[k];
      #pragma unroll
      for (int k = 0; k < 7; ++k) orow[448 + i*7 + k] = o3[k];
    }
  } else if (t < 192){
    const int rowL = (t - 128) >> 4;
    const int i    = 32 + (t & 15);
    if (row0 + rowL < n){
      const float* xr = xs + rowL*368;
      float*     orow = os + rowL*672;
      float s = xr[i];
      float p[3];
      #pragma unroll
      for (int k = 0; k < 3; ++k) p[k] = xr[64 + i*3 + k];

      float o0 = 0.f;
      float o1[3] = {0.f,0.f,0.f};
      float o2[5] = {0.f,0.f,0.f,0.f,0.f};

      tp_path<0,0,0>(&s,&s, 0.5f*mix[  0+i], &o0);
      tp_path<0,1,1>(&s, p, 0.5f*mix[ 64+i],  o1);
      tp_path<1,0,1>( p,&s, 0.5f*mix[144+i],  o1);
      tp_path<1,1,0>( p, p, 0.5f*mix[192+i], &o0);
      tp_path<1,1,1>( p, p, 0.5f*mix[240+i],  o1);
      tp_path<1,1,2>( p, p, 0.5f*mix[288+i],  o2);

      o0 += keep[i] * s;
      const float k1 = keep[64+i];
      #pragma unroll
      for (int k = 0; k < 3; ++k) o1[k] += k1 * p[k];

      orow[i] = o0;
      #pragma unroll
      for (int k = 0; k < 3; ++k) orow[ 64 + i*3 + k] = o1[k];
      #pragma unroll
      for (int k = 0; k < 5; ++k) orow[208 + i*5 + k] = o2[k];
    }
  } else {
    const int rowL = (t - 192) >> 4;
    const int i    = 48 + (t & 15);
    if (row0 + rowL < n){
      const float* xr = xs + rowL*368;
      float s = xr[i];
      float o0 = 0.f;
      tp_path<0,0,0>(&s,&s, 0.5f*mix[0+i], &o0);
      o0 += keep[i] * s;
      os[rowL*672 + i] = o0;
    }
  }
  __syncthreads();

  // ---- Phase 3: vectorized LDS -> global store of 4 rows (672 float4) ----
  {
    const long long nf4_out  = (long long)n * 168;           // total float4 in out
    const long long base_out = blk * (ROWS_PER_BLOCK * 168); // = blk*672
    const float4* srco = (const float4*)os;
    float4* __restrict__ dsto = (float4*)out;
    if (base_out + t < nf4_out)                 dsto[base_out + t]       = srco[t];
    if (base_out + 256 + t < nf4_out)           dsto[base_out + 256 + t] = srco[256+t];
    if (t < 160 && base_out + 512 + t < nf4_out) dsto[base_out + 512 + t] = srco[512+t];
  }
}

extern "C" void kernel_launch(void* const* d_in, const int* in_sizes, int n_in,
                              void* d_out, int out_size, void* d_ws, size_t ws_size,
                              hipStream_t stream)
{
  const float* x    = (const float*)d_in[0];
  const float* keep = (const float*)d_in[1];
  const float* mix  = (const float*)d_in[2];
  float* out = (float*)d_out;
  const int n = in_sizes[0] / 368;                 // 32768
  const int blocks = (n + ROWS_PER_BLOCK - 1) / ROWS_PER_BLOCK;
  selfmix_kernel<<<blocks, 256, 0, stream>>>(x, keep, mix, out, n);
}

// Round 2
// 137.191 us; speedup vs baseline: 1.0737x; 1.0737x over previous
//
#include <hip/hip_runtime.h>

// SelfMixing: CG tensor-product self-coupling, diagonal in channel.
// V3: revert to V1's barrier-free grid-level class split (V2's per-block wave
// specialization concentrated the heavy class-A work on 2/4 SIMDs -> 2x VALU
// serialization, 60us). Change vs V1: factor the runtime mix coefficient OUT
// of the CG inner loop -- accumulate W*pr with compile-time-constant W, then
// a single acc[m] += cmix*tmp[m] per output component. Removes ~200 runtime
// muls per class-A thread (~25-30% VALU reduction), memory behavior unchanged.

namespace cgc {

struct cplx { double re, im; };
constexpr cplx cmul(cplx a, cplx b){ return {a.re*b.re - a.im*b.im, a.re*b.im + a.im*b.re}; }

constexpr double cfact(int n){ double r = 1.0; for (int i = 2; i <= n; ++i) r *= i; return r; }
constexpr double cabsd(double x){ return x < 0 ? -x : x; }

constexpr double csqrtd(double x){
  if (x <= 0.0) return 0.0;
  double g = x > 1.0 ? x : 1.0;
  for (int i = 0; i < 48; ++i) g = 0.5*(g + x/g);
  return g;
}

constexpr double SQRT2 = csqrtd(2.0);

constexpr double cg_complex(int l1,int m1,int l2,int m2,int l3,int m3){
  if (m1 + m2 != m3) return 0.0;
  int lo = l1 > l2 ? l1 - l2 : l2 - l1;
  if (l3 < lo || l3 > l1 + l2) return 0.0;
  double pre = csqrtd((2*l3+1) * cfact(l1+l2-l3)*cfact(l1-l2+l3)*cfact(-l1+l2+l3)/cfact(l1+l2+l3+1));
  pre *= csqrtd(cfact(l1+m1)*cfact(l1-m1)*cfact(l2+m2)*cfact(l2-m2)*cfact(l3+m3)*cfact(l3-m3));
  int kmin = 0;
  if (l2-l3-m1 > kmin) kmin = l2-l3-m1;
  if (l1-l3+m2 > kmin) kmin = l1-l3+m2;
  int kmax = l1+l2-l3;
  if (l1-m1 < kmax) kmax = l1-m1;
  if (l2+m2 < kmax) kmax = l2+m2;
  double s = 0.0;
  for (int k = kmin; k <= kmax; ++k){
    double d = cfact(k)*cfact(l1+l2-l3-k)*cfact(l1-m1-k)*cfact(l2+m2-k)
             * cfact(l3-l2+m1+k)*cfact(l3-l1-m2+k);
    s += ((k & 1) ? -1.0 : 1.0) / d;
  }
  return pre * s;
}

// U[r][c]: rows = real m' (r = m'+l), cols = complex m (c = m+l)
constexpr cplx Uent(int l, int r, int c){
  int m = r - l;
  if (m > 0){
    if (c ==  m + l) return { ((m & 1) ? -1.0 : 1.0)/SQRT2, 0.0 };
    if (c == -m + l) return { 1.0/SQRT2, 0.0 };
    return {0.0, 0.0};
  } else if (m == 0){
    if (c == l) return {1.0, 0.0};
    return {0.0, 0.0};
  } else {
    int ma = -m;
    if (c ==  m + l) return { 0.0, 1.0/SQRT2 };                       // 1j/sqrt2
    if (c == -m + l) return { 0.0, -(((ma & 1) ? -1.0 : 1.0))/SQRT2 };// -1j*(-1)^m/sqrt2
    return {0.0, 0.0};
  }
}

template<int L1,int L2,int L3>
struct CGData { float w[(2*L1+1)*(2*L2+1)*(2*L3+1)]; };

template<int L1,int L2,int L3>
constexpr CGData<L1,L2,L3> make_cg(){
  constexpr int D1 = 2*L1+1, D2 = 2*L2+1, D3 = 2*L3+1;
  cplx U1[D1*D1] = {}; cplx U2[D2*D2] = {}; cplx U3c[D3*D3] = {};
  for (int r = 0; r < D1; ++r) for (int c = 0; c < D1; ++c) U1[r*D1+c] = Uent(L1, r, c);
  for (int r = 0; r < D2; ++r) for (int c = 0; c < D2; ++c) U2[r*D2+c] = Uent(L2, r, c);
  for (int r = 0; r < D3; ++r) for (int c = 0; c < D3; ++c){
    cplx u = Uent(L3, r, c); u.im = -u.im; U3c[r*D3+c] = u;
  }
  double Cc[D1*D2*D3] = {};
  for (int m1 = -L1; m1 <= L1; ++m1)
    for (int m2 = -L2; m2 <= L2; ++m2){
      int m3 = m1 + m2;
      if (m3 < -L3 || m3 > L3) continue;
      Cc[((m1+L1)*D2 + (m2+L2))*D3 + (m3+L3)] = cg_complex(L1,m1,L2,m2,L3,m3);
    }
  double re[D1*D2*D3] = {}; double im[D1*D2*D3] = {};
  for (int a = 0; a < D1; ++a)
    for (int b = 0; b < D2; ++b)
      for (int c = 0; c < D3; ++c){
        double sre = 0.0, sim = 0.0;
        for (int m = 0; m < D1; ++m)
          for (int n = 0; n < D2; ++n){
            int o = m + n - L1 - L2 + L3;   // only nonzero Cc slice
            if (o < 0 || o >= D3) continue;
            double cc = Cc[(m*D2+n)*D3 + o];
            if (cc == 0.0) continue;
            cplx p = cmul(cmul(U1[a*D1+m], U2[b*D2+n]), U3c[c*D3+o]);
            sre += p.re * cc; sim += p.im * cc;
          }
        re[(a*D2+b)*D3+c] = sre; im[(a*D2+b)*D3+c] = sim;
      }
  double mre = 0.0, mim = 0.0;
  for (int k = 0; k < D1*D2*D3; ++k){
    if (cabsd(re[k]) > mre) mre = cabsd(re[k]);
    if (cabsd(im[k]) > mim) mim = cabsd(im[k]);
  }
  CGData<L1,L2,L3> outv{};
  for (int k = 0; k < D1*D2*D3; ++k){
    double v = (mim > mre) ? im[k] : re[k];
    outv.w[k] = (cabsd(v) < 1e-10) ? 0.0f : (float)v;
  }
  return outv;
}

} // namespace cgc

template<int L1,int L2,int L3>
__device__ __forceinline__ void tp_path(const float* xa, const float* xb, float cmix, float* acc){
  constexpr cgc::CGData<L1,L2,L3> cg = cgc::make_cg<L1,L2,L3>();
  constexpr int D1 = 2*L1+1, D2 = 2*L2+1, D3 = 2*L3+1;
  float tmp[D3];
  #pragma unroll
  for (int m = 0; m < D3; ++m) tmp[m] = 0.0f;
  #pragma unroll
  for (int a = 0; a < D1; ++a){
    #pragma unroll
    for (int b = 0; b < D2; ++b){
      const float pr = xa[a] * xb[b];   // CSE'd across paths sharing operands
      #pragma unroll
      for (int m = 0; m < D3; ++m){
        const float W = cg.w[(a*D2+b)*D3 + m];
        if (W != 0.0f) tmp[m] += W * pr;   // constant-weight FMA; zeros DCE'd
      }
    }
  }
  #pragma unroll
  for (int m = 0; m < D3; ++m) acc[m] += cmix * tmp[m];  // runtime coeff applied ONCE
}

// Layout constants (match reference):
// OFF_IN  = [0, 64, 208, 368]; OFF_OUT = [0, 64, 208, 448, 672]
// mix bases per path order:
//  (0,0,0):0 (0,1,1):64 (0,2,2):112 (1,0,1):144 (1,1,0):192 (1,1,1):240 (1,1,2):288
//  (1,2,1):336 (1,2,2):368 (1,2,3):400 (2,0,2):432 (2,1,1):464 (2,1,2):496 (2,1,3):528
//  (2,2,0):560 (2,2,1):592 (2,2,2):624 (2,2,3):656
// keep chan: l0 -> i, l1 -> 64+i, l2 -> 112+i

__global__ __launch_bounds__(256) void selfmix_kernel(
    const float* __restrict__ x, const float* __restrict__ keep,
    const float* __restrict__ mix, float* __restrict__ out, int n)
{
  const long long gid = (long long)blockIdx.x * 256 + threadIdx.x;
  const long long nA = (long long)n * 32;   // class A threads: channels 0..31 (all l)
  const long long nB = (long long)n * 16;   // class B: channels 32..47 (l0,l1); class C: 48..63 (l0)

  if (gid < nA){
    const int i   = (int)(gid & 31);
    const int row = (int)(gid >> 5);
    const float* xr = x + (long long)row * 368;
    float*     orow = out + (long long)row * 672;
    float s = xr[i];
    float p[3], d[5];
    #pragma unroll
    for (int k = 0; k < 3; ++k) p[k] = xr[64 + i*3 + k];
    #pragma unroll
    for (int k = 0; k < 5; ++k) d[k] = xr[208 + i*5 + k];

    float o0 = 0.f;
    float o1[3] = {0.f,0.f,0.f};
    float o2[5] = {0.f,0.f,0.f,0.f,0.f};
    float o3[7] = {0.f,0.f,0.f,0.f,0.f,0.f,0.f};

    tp_path<0,0,0>(&s,&s, 0.5f*mix[  0+i], &o0);
    tp_path<0,1,1>(&s, p, 0.5f*mix[ 64+i],  o1);
    tp_path<0,2,2>(&s, d, 0.5f*mix[112+i],  o2);
    tp_path<1,0,1>( p,&s, 0.5f*mix[144+i],  o1);
    tp_path<1,1,0>( p, p, 0.5f*mix[192+i], &o0);
    tp_path<1,1,1>( p, p, 0.5f*mix[240+i],  o1);
    tp_path<1,1,2>( p, p, 0.5f*mix[288+i],  o2);
    tp_path<1,2,1>( p, d, 0.5f*mix[336+i],  o1);
    tp_path<1,2,2>( p, d, 0.5f*mix[368+i],  o2);
    tp_path<1,2,3>( p, d, 0.5f*mix[400+i],  o3);
    tp_path<2,0,2>( d,&s, 0.5f*mix[432+i],  o2);
    tp_path<2,1,1>( d, p, 0.5f*mix[464+i],  o1);
    tp_path<2,1,2>( d, p, 0.5f*mix[496+i],  o2);
    tp_path<2,1,3>( d, p, 0.5f*mix[528+i],  o3);
    tp_path<2,2,0>( d, d, 0.5f*mix[560+i], &o0);
    tp_path<2,2,1>( d, d, 0.5f*mix[592+i],  o1);
    tp_path<2,2,2>( d, d, 0.5f*mix[624+i],  o2);
    tp_path<2,2,3>( d, d, 0.5f*mix[656+i],  o3);

    // keep path
    o0 += keep[i] * s;
    const float k1 = keep[64+i], k2 = keep[112+i];
    #pragma unroll
    for (int k = 0; k < 3; ++k) o1[k] += k1 * p[k];
    #pragma unroll
    for (int k = 0; k < 5; ++k) o2[k] += k2 * d[k];

    orow[i] = o0;
    #pragma unroll
    for (int k = 0; k < 3; ++k) orow[ 64 + i*3 + k] = o1[k];
    #pragma unroll
    for (int k = 0; k < 5; ++k) orow[208 + i*5 + k] = o2[k];
    #pragma unroll
    for (int k = 0; k < 7; ++k) orow[448 + i*7 + k] = o3[k];

  } else if (gid < nA + nB){
    const long long t = gid - nA;
    const int i   = 32 + (int)(t & 15);
    const int row = (int)(t >> 4);
    const float* xr = x + (long long)row * 368;
    float*     orow = out + (long long)row * 672;
    float s = xr[i];
    float p[3];
    #pragma unroll
    for (int k = 0; k < 3; ++k) p[k] = xr[64 + i*3 + k];

    float o0 = 0.f;
    float o1[3] = {0.f,0.f,0.f};
    float o2[5] = {0.f,0.f,0.f,0.f,0.f};

    tp_path<0,0,0>(&s,&s, 0.5f*mix[  0+i], &o0);
    tp_path<0,1,1>(&s, p, 0.5f*mix[ 64+i],  o1);
    tp_path<1,0,1>( p,&s, 0.5f*mix[144+i],  o1);
    tp_path<1,1,0>( p, p, 0.5f*mix[192+i], &o0);
    tp_path<1,1,1>( p, p, 0.5f*mix[240+i],  o1);
    tp_path<1,1,2>( p, p, 0.5f*mix[288+i],  o2);

    o0 += keep[i] * s;
    const float k1 = keep[64+i];
    #pragma unroll
    for (int k = 0; k < 3; ++k) o1[k] += k1 * p[k];

    orow[i] = o0;
    #pragma unroll
    for (int k = 0; k < 3; ++k) orow[ 64 + i*3 + k] = o1[k];
    #pragma unroll
    for (int k = 0; k < 5; ++k) orow[208 + i*5 + k] = o2[k];

  } else if (gid < nA + 2*nB){
    const long long t = gid - nA - nB;
    const int i   = 48 + (int)(t & 15);
    const int row = (int)(t >> 4);
    const float* xr = x + (long long)row * 368;
    float s = xr[i];
    float o0 = 0.f;
    tp_path<0,0,0>(&s,&s, 0.5f*mix[0+i], &o0);
    o0 += keep[i] * s;
    out[(long long)row * 672 + i] = o0;
  }
}

extern "C" void kernel_launch(void* const* d_in, const int* in_sizes, int n_in,
                              void* d_out, int out_size, void* d_ws, size_t ws_size,
                              hipStream_t stream)
{
  const float* x    = (const float*)d_in[0];
  const float* keep = (const float*)d_in[1];
  const float* mix  = (const float*)d_in[2];
  float* out = (float*)d_out;
  const int n = in_sizes[0] / 368;          // 32768
  const long long total = (long long)n * 64; // one thread per (row, channel-slot)
  const int blocks = (int)((total + 255) / 256);
  selfmix_kernel<<<blocks, 256, 0, stream>>>(x, keep, mix, out, n);
}

// Round 3
// 135.061 us; speedup vs baseline: 1.0906x; 1.0158x over previous
//
#include <hip/hip_runtime.h>

// SelfMixing: CG tensor-product self-coupling, diagonal in channel.
// V4: class-PURE blocks (V1's proven SIMD balance — V2 failed because heavy
// waves were pinned to SIMD0/1 via wave_id%4) + LDS-staged float4 I/O for
// class A only (77% of HBM traffic, worst access pattern). Class-A block =
// 8 rows x 32 channels; x staged in via 92 f4/row, compute reads LDS
// (strides 3/5/7 coprime with 32 banks -> conflict-free), results staged to
// a compact 512-float/row layout, stored as 128 f4/row (all 4 output
// segments are 16B-aligned, f4-multiple length). Classes B/C keep direct
// access (64B-aligned segments, 23% of traffic).

namespace cgc {

struct cplx { double re, im; };
constexpr cplx cmul(cplx a, cplx b){ return {a.re*b.re - a.im*b.im, a.re*b.im + a.im*b.re}; }

constexpr double cfact(int n){ double r = 1.0; for (int i = 2; i <= n; ++i) r *= i; return r; }
constexpr double cabsd(double x){ return x < 0 ? -x : x; }

constexpr double csqrtd(double x){
  if (x <= 0.0) return 0.0;
  double g = x > 1.0 ? x : 1.0;
  for (int i = 0; i < 48; ++i) g = 0.5*(g + x/g);
  return g;
}

constexpr double SQRT2 = csqrtd(2.0);

constexpr double cg_complex(int l1,int m1,int l2,int m2,int l3,int m3){
  if (m1 + m2 != m3) return 0.0;
  int lo = l1 > l2 ? l1 - l2 : l2 - l1;
  if (l3 < lo || l3 > l1 + l2) return 0.0;
  double pre = csqrtd((2*l3+1) * cfact(l1+l2-l3)*cfact(l1-l2+l3)*cfact(-l1+l2+l3)/cfact(l1+l2+l3+1));
  pre *= csqrtd(cfact(l1+m1)*cfact(l1-m1)*cfact(l2+m2)*cfact(l2-m2)*cfact(l3+m3)*cfact(l3-m3));
  int kmin = 0;
  if (l2-l3-m1 > kmin) kmin = l2-l3-m1;
  if (l1-l3+m2 > kmin) kmin = l1-l3+m2;
  int kmax = l1+l2-l3;
  if (l1-m1 < kmax) kmax = l1-m1;
  if (l2+m2 < kmax) kmax = l2+m2;
  double s = 0.0;
  for (int k = kmin; k <= kmax; ++k){
    double d = cfact(k)*cfact(l1+l2-l3-k)*cfact(l1-m1-k)*cfact(l2+m2-k)
             * cfact(l3-l2+m1+k)*cfact(l3-l1-m2+k);
    s += ((k & 1) ? -1.0 : 1.0) / d;
  }
  return pre * s;
}

// U[r][c]: rows = real m' (r = m'+l), cols = complex m (c = m+l)
constexpr cplx Uent(int l, int r, int c){
  int m = r - l;
  if (m > 0){
    if (c ==  m + l) return { ((m & 1) ? -1.0 : 1.0)/SQRT2, 0.0 };
    if (c == -m + l) return { 1.0/SQRT2, 0.0 };
    return {0.0, 0.0};
  } else if (m == 0){
    if (c == l) return {1.0, 0.0};
    return {0.0, 0.0};
  } else {
    int ma = -m;
    if (c ==  m + l) return { 0.0, 1.0/SQRT2 };                       // 1j/sqrt2
    if (c == -m + l) return { 0.0, -(((ma & 1) ? -1.0 : 1.0))/SQRT2 };// -1j*(-1)^m/sqrt2
    return {0.0, 0.0};
  }
}

template<int L1,int L2,int L3>
struct CGData { float w[(2*L1+1)*(2*L2+1)*(2*L3+1)]; };

template<int L1,int L2,int L3>
constexpr CGData<L1,L2,L3> make_cg(){
  constexpr int D1 = 2*L1+1, D2 = 2*L2+1, D3 = 2*L3+1;
  cplx U1[D1*D1] = {}; cplx U2[D2*D2] = {}; cplx U3c[D3*D3] = {};
  for (int r = 0; r < D1; ++r) for (int c = 0; c < D1; ++c) U1[r*D1+c] = Uent(L1, r, c);
  for (int r = 0; r < D2; ++r) for (int c = 0; c < D2; ++c) U2[r*D2+c] = Uent(L2, r, c);
  for (int r = 0; r < D3; ++r) for (int c = 0; c < D3; ++c){
    cplx u = Uent(L3, r, c); u.im = -u.im; U3c[r*D3+c] = u;
  }
  double Cc[D1*D2*D3] = {};
  for (int m1 = -L1; m1 <= L1; ++m1)
    for (int m2 = -L2; m2 <= L2; ++m2){
      int m3 = m1 + m2;
      if (m3 < -L3 || m3 > L3) continue;
      Cc[((m1+L1)*D2 + (m2+L2))*D3 + (m3+L3)] = cg_complex(L1,m1,L2,m2,L3,m3);
    }
  double re[D1*D2*D3] = {}; double im[D1*D2*D3] = {};
  for (int a = 0; a < D1; ++a)
    for (int b = 0; b < D2; ++b)
      for (int c = 0; c < D3; ++c){
        double sre = 0.0, sim = 0.0;
        for (int m = 0; m < D1; ++m)
          for (int n = 0; n < D2; ++n){
            int o = m + n - L1 - L2 + L3;   // only nonzero Cc slice
            if (o < 0 || o >= D3) continue;
            double cc = Cc[(m*D2+n)*D3 + o];
            if (cc == 0.0) continue;
            cplx p = cmul(cmul(U1[a*D1+m], U2[b*D2+n]), U3c[c*D3+o]);
            sre += p.re * cc; sim += p.im * cc;
          }
        re[(a*D2+b)*D3+c] = sre; im[(a*D2+b)*D3+c] = sim;
      }
  double mre = 0.0, mim = 0.0;
  for (int k = 0; k < D1*D2*D3; ++k){
    if (cabsd(re[k]) > mre) mre = cabsd(re[k]);
    if (cabsd(im[k]) > mim) mim = cabsd(im[k]);
  }
  CGData<L1,L2,L3> outv{};
  for (int k = 0; k < D1*D2*D3; ++k){
    double v = (mim > mre) ? im[k] : re[k];
    outv.w[k] = (cabsd(v) < 1e-10) ? 0.0f : (float)v;
  }
  return outv;
}

} // namespace cgc

template<int L1,int L2,int L3>
__device__ __forceinline__ void tp_path(const float* xa, const float* xb, float cmix, float* acc){
  constexpr cgc::CGData<L1,L2,L3> cg = cgc::make_cg<L1,L2,L3>();
  constexpr int D1 = 2*L1+1, D2 = 2*L2+1, D3 = 2*L3+1;
  float tmp[D3];
  #pragma unroll
  for (int m = 0; m < D3; ++m) tmp[m] = 0.0f;
  #pragma unroll
  for (int a = 0; a < D1; ++a){
    #pragma unroll
    for (int b = 0; b < D2; ++b){
      const float pr = xa[a] * xb[b];   // CSE'd across paths sharing operands
      #pragma unroll
      for (int m = 0; m < D3; ++m){
        const float W = cg.w[(a*D2+b)*D3 + m];
        if (W != 0.0f) tmp[m] += W * pr;   // constant-weight FMA; zeros DCE'd
      }
    }
  }
  #pragma unroll
  for (int m = 0; m < D3; ++m) acc[m] += cmix * tmp[m];  // runtime coeff applied ONCE
}

// Layout constants (match reference):
// OFF_IN  = [0, 64, 208, 368]; OFF_OUT = [0, 64, 208, 448, 672]
// mix bases per path order:
//  (0,0,0):0 (0,1,1):64 (0,2,2):112 (1,0,1):144 (1,1,0):192 (1,1,1):240 (1,1,2):288
//  (1,2,1):336 (1,2,2):368 (1,2,3):400 (2,0,2):432 (2,1,1):464 (2,1,2):496 (2,1,3):528
//  (2,2,0):560 (2,2,1):592 (2,2,2):624 (2,2,3):656
// keep chan: l0 -> i, l1 -> 64+i, l2 -> 112+i
//
// Class-A (ch 0..31) output floats per row: l0 [0,32) l1 [64,160) l2 [208,368)
// l3 [448,672) -> 512 floats. Compact LDS layout per row:
//   [0,32) o0 | [32,128) o1 (32+3i+k) | [128,288) o2 (128+5i+k) | [288,512) o3 (288+7i+k)
// f4 writeback map (k = compact f4 slot 0..127, out row = 168 f4):
//   k<8 -> k | k<32 -> k+8 | k<72 -> k+20 | else -> k+40

__global__ __launch_bounds__(256) void selfmix_kernel(
    const float* __restrict__ x, const float* __restrict__ keep,
    const float* __restrict__ mix, float* __restrict__ out, int n)
{
  __shared__ __align__(16) float buf[8 * 512];   // 16 KiB, reused xs -> os

  const int t   = threadIdx.x;
  const int blk = blockIdx.x;
  const int bA  = (n + 7)  >> 3;   // class-A blocks: 8 rows x 32 ch
  const int bB  = (n + 15) >> 4;   // class-B blocks: 16 rows x 16 ch

  if (blk < bA){
    // ======================= CLASS A (staged) =======================
    const long long row0 = (long long)blk * 8;
    float4* buf4 = (float4*)buf;

    // ---- P1: global -> LDS, 8 rows x 92 f4 = 736 f4, float4-coalesced ----
    {
      const long long nf4 = (long long)n * 92;
      const long long base = row0 * 92;
      const float4* __restrict__ x4 = (const float4*)x;
      if (base + t < nf4)              buf4[t]       = x4[base + t];
      if (base + 256 + t < nf4)        buf4[256 + t] = x4[base + 256 + t];
      if (t < 224 && base + 512 + t < nf4) buf4[512 + t] = x4[base + 512 + t];
    }
    __syncthreads();

    // ---- P2: compute. wave lanes: 2 rows x 32 ch, every wave pure-heavy ----
    const int rowL = t >> 5;
    const int i    = t & 31;
    const bool live = (row0 + rowL) < n;

    float s = 0.f, p[3] = {0.f,0.f,0.f}, d[5] = {0.f,0.f,0.f,0.f,0.f};
    if (live){
      const float* xr = buf + rowL * 368;
      s = xr[i];
      #pragma unroll
      for (int k = 0; k < 3; ++k) p[k] = xr[64 + i*3 + k];
      #pragma unroll
      for (int k = 0; k < 5; ++k) d[k] = xr[208 + i*5 + k];
    }

    float o0 = 0.f;
    float o1[3] = {0.f,0.f,0.f};
    float o2[5] = {0.f,0.f,0.f,0.f,0.f};
    float o3[7] = {0.f,0.f,0.f,0.f,0.f,0.f,0.f};

    tp_path<0,0,0>(&s,&s, 0.5f*mix[  0+i], &o0);
    tp_path<0,1,1>(&s, p, 0.5f*mix[ 64+i],  o1);
    tp_path<0,2,2>(&s, d, 0.5f*mix[112+i],  o2);
    tp_path<1,0,1>( p,&s, 0.5f*mix[144+i],  o1);
    tp_path<1,1,0>( p, p, 0.5f*mix[192+i], &o0);
    tp_path<1,1,1>( p, p, 0.5f*mix[240+i],  o1);
    tp_path<1,1,2>( p, p, 0.5f*mix[288+i],  o2);
    tp_path<1,2,1>( p, d, 0.5f*mix[336+i],  o1);
    tp_path<1,2,2>( p, d, 0.5f*mix[368+i],  o2);
    tp_path<1,2,3>( p, d, 0.5f*mix[400+i],  o3);
    tp_path<2,0,2>( d,&s, 0.5f*mix[432+i],  o2);
    tp_path<2,1,1>( d, p, 0.5f*mix[464+i],  o1);
    tp_path<2,1,2>( d, p, 0.5f*mix[496+i],  o2);
    tp_path<2,1,3>( d, p, 0.5f*mix[528+i],  o3);
    tp_path<2,2,0>( d, d, 0.5f*mix[560+i], &o0);
    tp_path<2,2,1>( d, d, 0.5f*mix[592+i],  o1);
    tp_path<2,2,2>( d, d, 0.5f*mix[624+i],  o2);
    tp_path<2,2,3>( d, d, 0.5f*mix[656+i],  o3);

    // keep path
    o0 += keep[i] * s;
    const float k1 = keep[64+i], k2 = keep[112+i];
    #pragma unroll
    for (int k = 0; k < 3; ++k) o1[k] += k1 * p[k];
    #pragma unroll
    for (int k = 0; k < 5; ++k) o2[k] += k2 * d[k];

    __syncthreads();   // all xs reads done; buf can be overwritten

    if (live){
      float* orw = buf + rowL * 512;   // compact per-row layout
      orw[i] = o0;                     // strides 1,3,5,7 all coprime w/ 32 banks
      #pragma unroll
      for (int k = 0; k < 3; ++k) orw[ 32 + i*3 + k] = o1[k];
      #pragma unroll
      for (int k = 0; k < 5; ++k) orw[128 + i*5 + k] = o2[k];
      #pragma unroll
      for (int k = 0; k < 7; ++k) orw[288 + i*7 + k] = o3[k];
    }
    __syncthreads();

    // ---- P3: LDS -> global, 8 rows x 128 f4 = 1024 f4, float4-coalesced ----
    {
      const float4* bo4 = (const float4*)buf;
      float4* __restrict__ o4 = (float4*)out;
      #pragma unroll
      for (int rnd = 0; rnd < 4; ++rnd){
        const int sidx = rnd*256 + t;       // 0..1023
        const int r = sidx >> 7;
        const int k = sidx & 127;
        const long long row = row0 + r;
        if (row < n){
          const int g = k + (k < 8 ? 0 : (k < 32 ? 8 : (k < 72 ? 20 : 40)));
          o4[row*168 + g] = bo4[sidx];
        }
      }
    }

  } else if (blk < bA + bB){
    // ======================= CLASS B (direct, V1) =======================
    const long long t2 = (long long)(blk - bA) * 256 + t;
    const int i        = 32 + (int)(t2 & 15);
    const long long row = t2 >> 4;
    if (row < n){
      const float* xr = x + row * 368;
      float*     orow = out + row * 672;
      float s = xr[i];
      float p[3];
      #pragma unroll
      for (int k = 0; k < 3; ++k) p[k] = xr[64 + i*3 + k];

      float o0 = 0.f;
      float o1[3] = {0.f,0.f,0.f};
      float o2[5] = {0.f,0.f,0.f,0.f,0.f};

      tp_path<0,0,0>(&s,&s, 0.5f*mix[  0+i], &o0);
      tp_path<0,1,1>(&s, p, 0.5f*mix[ 64+i],  o1);
      tp_path<1,0,1>( p,&s, 0.5f*mix[144+i],  o1);
      tp_path<1,1,0>( p, p, 0.5f*mix[192+i], &o0);
      tp_path<1,1,1>( p, p, 0.5f*mix[240+i],  o1);
      tp_path<1,1,2>( p, p, 0.5f*mix[288+i],  o2);

      o0 += keep[i] * s;
      const float k1 = keep[64+i];
      #pragma unroll
      for (int k = 0; k < 3; ++k) o1[k] += k1 * p[k];

      orow[i] = o0;
      #pragma unroll
      for (int k = 0; k < 3; ++k) orow[ 64 + i*3 + k] = o1[k];
      #pragma unroll
      for (int k = 0; k < 5; ++k) orow[208 + i*5 + k] = o2[k];
    }

  } else {
    // ======================= CLASS C (direct, V1) =======================
    const long long t2 = (long long)(blk - bA - bB) * 256 + t;
    const int i        = 48 + (int)(t2 & 15);
    const long long row = t2 >> 4;
    if (row < n){
      float s = x[row * 368 + i];
      float o0 = 0.f;
      tp_path<0,0,0>(&s,&s, 0.5f*mix[0+i], &o0);
      o0 += keep[i] * s;
      out[row * 672 + i] = o0;
    }
  }
}

extern "C" void kernel_launch(void* const* d_in, const int* in_sizes, int n_in,
                              void* d_out, int out_size, void* d_ws, size_t ws_size,
                              hipStream_t stream)
{
  const float* x    = (const float*)d_in[0];
  const float* keep = (const float*)d_in[1];
  const float* mix  = (const float*)d_in[2];
  float* out = (float*)d_out;
  const int n  = in_sizes[0] / 368;      // 32768
  const int bA = (n + 7)  >> 3;
  const int bB = (n + 15) >> 4;
  const int blocks = bA + 2 * bB;
  selfmix_kernel<<<blocks, 256, 0, stream>>>(x, keep, mix, out, n);
}

// Round 4
// 131.641 us; speedup vs baseline: 1.1189x; 1.0260x over previous
//
#include <hip/hip_runtime.h>

// SelfMixing: CG tensor-product self-coupling, diagonal in channel.
// V5: ONE uniform block type (kills the grid-level B/C serial tail of V1/V3/V4
// and the partial-cacheline RMW from 3 blocks writing each output row).
// Block = 8 rows x 256 threads:
//   P1: 736 contiguous float4 (8 rows of x) -> LDS
//   P2a: EVERY thread does one class-A job (8x32 = 256 jobs -> heavy work
//        spread over all 4 waves; V2 failed by pinning A to waves 0-1)
//   P2b: waves 0-1 do the 128 class-B jobs; P2c: waves 2-3 do the 128 C jobs
//        (wave-uniform branches, both light)
//   P3: complete 672-float rows from LDS -> 1344 contiguous float4 stores
// All HBM traffic is full-line float4; each output row written by one block.

namespace cgc {

struct cplx { double re, im; };
constexpr cplx cmul(cplx a, cplx b){ return {a.re*b.re - a.im*b.im, a.re*b.im + a.im*b.re}; }

constexpr double cfact(int n){ double r = 1.0; for (int i = 2; i <= n; ++i) r *= i; return r; }
constexpr double cabsd(double x){ return x < 0 ? -x : x; }

constexpr double csqrtd(double x){
  if (x <= 0.0) return 0.0;
  double g = x > 1.0 ? x : 1.0;
  for (int i = 0; i < 48; ++i) g = 0.5*(g + x/g);
  return g;
}

constexpr double SQRT2 = csqrtd(2.0);

constexpr double cg_complex(int l1,int m1,int l2,int m2,int l3,int m3){
  if (m1 + m2 != m3) return 0.0;
  int lo = l1 > l2 ? l1 - l2 : l2 - l1;
  if (l3 < lo || l3 > l1 + l2) return 0.0;
  double pre = csqrtd((2*l3+1) * cfact(l1+l2-l3)*cfact(l1-l2+l3)*cfact(-l1+l2+l3)/cfact(l1+l2+l3+1));
  pre *= csqrtd(cfact(l1+m1)*cfact(l1-m1)*cfact(l2+m2)*cfact(l2-m2)*cfact(l3+m3)*cfact(l3-m3));
  int kmin = 0;
  if (l2-l3-m1 > kmin) kmin = l2-l3-m1;
  if (l1-l3+m2 > kmin) kmin = l1-l3+m2;
  int kmax = l1+l2-l3;
  if (l1-m1 < kmax) kmax = l1-m1;
  if (l2+m2 < kmax) kmax = l2+m2;
  double s = 0.0;
  for (int k = kmin; k <= kmax; ++k){
    double d = cfact(k)*cfact(l1+l2-l3-k)*cfact(l1-m1-k)*cfact(l2+m2-k)
             * cfact(l3-l2+m1+k)*cfact(l3-l1-m2+k);
    s += ((k & 1) ? -1.0 : 1.0) / d;
  }
  return pre * s;
}

// U[r][c]: rows = real m' (r = m'+l), cols = complex m (c = m+l)
constexpr cplx Uent(int l, int r, int c){
  int m = r - l;
  if (m > 0){
    if (c ==  m + l) return { ((m & 1) ? -1.0 : 1.0)/SQRT2, 0.0 };
    if (c == -m + l) return { 1.0/SQRT2, 0.0 };
    return {0.0, 0.0};
  } else if (m == 0){
    if (c == l) return {1.0, 0.0};
    return {0.0, 0.0};
  } else {
    int ma = -m;
    if (c ==  m + l) return { 0.0, 1.0/SQRT2 };                       // 1j/sqrt2
    if (c == -m + l) return { 0.0, -(((ma & 1) ? -1.0 : 1.0))/SQRT2 };// -1j*(-1)^m/sqrt2
    return {0.0, 0.0};
  }
}

template<int L1,int L2,int L3>
struct CGData { float w[(2*L1+1)*(2*L2+1)*(2*L3+1)]; };

template<int L1,int L2,int L3>
constexpr CGData<L1,L2,L3> make_cg(){
  constexpr int D1 = 2*L1+1, D2 = 2*L2+1, D3 = 2*L3+1;
  cplx U1[D1*D1] = {}; cplx U2[D2*D2] = {}; cplx U3c[D3*D3] = {};
  for (int r = 0; r < D1; ++r) for (int c = 0; c < D1; ++c) U1[r*D1+c] = Uent(L1, r, c);
  for (int r = 0; r < D2; ++r) for (int c = 0; c < D2; ++c) U2[r*D2+c] = Uent(L2, r, c);
  for (int r = 0; r < D3; ++r) for (int c = 0; c < D3; ++c){
    cplx u = Uent(L3, r, c); u.im = -u.im; U3c[r*D3+c] = u;
  }
  double Cc[D1*D2*D3] = {};
  for (int m1 = -L1; m1 <= L1; ++m1)
    for (int m2 = -L2; m2 <= L2; ++m2){
      int m3 = m1 + m2;
      if (m3 < -L3 || m3 > L3) continue;
      Cc[((m1+L1)*D2 + (m2+L2))*D3 + (m3+L3)] = cg_complex(L1,m1,L2,m2,L3,m3);
    }
  double re[D1*D2*D3] = {}; double im[D1*D2*D3] = {};
  for (int a = 0; a < D1; ++a)
    for (int b = 0; b < D2; ++b)
      for (int c = 0; c < D3; ++c){
        double sre = 0.0, sim = 0.0;
        for (int m = 0; m < D1; ++m)
          for (int n = 0; n < D2; ++n){
            int o = m + n - L1 - L2 + L3;   // only nonzero Cc slice
            if (o < 0 || o >= D3) continue;
            double cc = Cc[(m*D2+n)*D3 + o];
            if (cc == 0.0) continue;
            cplx p = cmul(cmul(U1[a*D1+m], U2[b*D2+n]), U3c[c*D3+o]);
            sre += p.re * cc; sim += p.im * cc;
          }
        re[(a*D2+b)*D3+c] = sre; im[(a*D2+b)*D3+c] = sim;
      }
  double mre = 0.0, mim = 0.0;
  for (int k = 0; k < D1*D2*D3; ++k){
    if (cabsd(re[k]) > mre) mre = cabsd(re[k]);
    if (cabsd(im[k]) > mim) mim = cabsd(im[k]);
  }
  CGData<L1,L2,L3> outv{};
  for (int k = 0; k < D1*D2*D3; ++k){
    double v = (mim > mre) ? im[k] : re[k];
    outv.w[k] = (cabsd(v) < 1e-10) ? 0.0f : (float)v;
  }
  return outv;
}

} // namespace cgc

template<int L1,int L2,int L3>
__device__ __forceinline__ void tp_path(const float* xa, const float* xb, float cmix, float* acc){
  constexpr cgc::CGData<L1,L2,L3> cg = cgc::make_cg<L1,L2,L3>();
  constexpr int D1 = 2*L1+1, D2 = 2*L2+1, D3 = 2*L3+1;
  float tmp[D3];
  #pragma unroll
  for (int m = 0; m < D3; ++m) tmp[m] = 0.0f;
  #pragma unroll
  for (int a = 0; a < D1; ++a){
    #pragma unroll
    for (int b = 0; b < D2; ++b){
      const float pr = xa[a] * xb[b];   // CSE'd across paths sharing operands
      #pragma unroll
      for (int m = 0; m < D3; ++m){
        const float W = cg.w[(a*D2+b)*D3 + m];
        if (W != 0.0f) tmp[m] += W * pr;   // constant-weight FMA; zeros DCE'd
      }
    }
  }
  #pragma unroll
  for (int m = 0; m < D3; ++m) acc[m] += cmix * tmp[m];  // runtime coeff applied ONCE
}

// Layout constants (match reference):
// OFF_IN  = [0, 64, 208, 368]; OFF_OUT = [0, 64, 208, 448, 672]
// mix bases per path order:
//  (0,0,0):0 (0,1,1):64 (0,2,2):112 (1,0,1):144 (1,1,0):192 (1,1,1):240 (1,1,2):288
//  (1,2,1):336 (1,2,2):368 (1,2,3):400 (2,0,2):432 (2,1,1):464 (2,1,2):496 (2,1,3):528
//  (2,2,0):560 (2,2,1):592 (2,2,2):624 (2,2,3):656
// keep chan: l0 -> i, l1 -> 64+i, l2 -> 112+i
//
// Output-row coverage: class A (ch 0..31) writes floats [0,32)+[64,160)+
// [208,368)+[448,672); class B (ch 32..47) [32,48)+[160,208)+[368,448);
// class C (ch 48..63) [48,64). Union = [0,672) -> P3 is a straight copy.

#define RPB 8   // rows per block

__global__ __launch_bounds__(256) void selfmix_kernel(
    const float* __restrict__ x, const float* __restrict__ keep,
    const float* __restrict__ mix, float* __restrict__ out, int n)
{
  __shared__ __align__(16) float xs[RPB * 368];   // 11776 B
  __shared__ __align__(16) float os[RPB * 672];   // 21504 B

  const int t = threadIdx.x;
  const long long blk  = blockIdx.x;
  const long long row0 = blk * RPB;

  // ---- P1: global -> LDS, 8 rows x 92 f4 = 736 f4, fully contiguous ----
  {
    const long long nf4  = (long long)n * 92;
    const long long base = row0 * 92;
    const float4* __restrict__ x4 = (const float4*)x;
    float4* xs4 = (float4*)xs;
    if (base + t < nf4)                   xs4[t]       = x4[base + t];
    if (base + 256 + t < nf4)             xs4[256 + t] = x4[base + 256 + t];
    if (t < 224 && base + 512 + t < nf4)  xs4[512 + t] = x4[base + 512 + t];
  }
  __syncthreads();

  // ---- P2a: class-A job for EVERY thread (8 rows x 32 ch = 256 jobs) ----
  {
    const int rowL = t >> 5;          // 0..7
    const int i    = t & 31;          // 0..31
    if (row0 + rowL < n){
      const float* xr = xs + rowL * 368;
      float*     orw  = os + rowL * 672;
      float s = xr[i];
      float p[3], d[5];
      #pragma unroll
      for (int k = 0; k < 3; ++k) p[k] = xr[64 + i*3 + k];
      #pragma unroll
      for (int k = 0; k < 5; ++k) d[k] = xr[208 + i*5 + k];

      float o0 = 0.f;
      float o1[3] = {0.f,0.f,0.f};
      float o2[5] = {0.f,0.f,0.f,0.f,0.f};
      float o3[7] = {0.f,0.f,0.f,0.f,0.f,0.f,0.f};

      tp_path<0,0,0>(&s,&s, 0.5f*mix[  0+i], &o0);
      tp_path<0,1,1>(&s, p, 0.5f*mix[ 64+i],  o1);
      tp_path<0,2,2>(&s, d, 0.5f*mix[112+i],  o2);
      tp_path<1,0,1>( p,&s, 0.5f*mix[144+i],  o1);
      tp_path<1,1,0>( p, p, 0.5f*mix[192+i], &o0);
      tp_path<1,1,1>( p, p, 0.5f*mix[240+i],  o1);
      tp_path<1,1,2>( p, p, 0.5f*mix[288+i],  o2);
      tp_path<1,2,1>( p, d, 0.5f*mix[336+i],  o1);
      tp_path<1,2,2>( p, d, 0.5f*mix[368+i],  o2);
      tp_path<1,2,3>( p, d, 0.5f*mix[400+i],  o3);
      tp_path<2,0,2>( d,&s, 0.5f*mix[432+i],  o2);
      tp_path<2,1,1>( d, p, 0.5f*mix[464+i],  o1);
      tp_path<2,1,2>( d, p, 0.5f*mix[496+i],  o2);
      tp_path<2,1,3>( d, p, 0.5f*mix[528+i],  o3);
      tp_path<2,2,0>( d, d, 0.5f*mix[560+i], &o0);
      tp_path<2,2,1>( d, d, 0.5f*mix[592+i],  o1);
      tp_path<2,2,2>( d, d, 0.5f*mix[624+i],  o2);
      tp_path<2,2,3>( d, d, 0.5f*mix[656+i],  o3);

      o0 += keep[i] * s;
      const float k1 = keep[64+i], k2 = keep[112+i];
      #pragma unroll
      for (int k = 0; k < 3; ++k) o1[k] += k1 * p[k];
      #pragma unroll
      for (int k = 0; k < 5; ++k) o2[k] += k2 * d[k];

      orw[i] = o0;
      #pragma unroll
      for (int k = 0; k < 3; ++k) orw[ 64 + i*3 + k] = o1[k];   // stride 3: conflict-free
      #pragma unroll
      for (int k = 0; k < 5; ++k) orw[208 + i*5 + k] = o2[k];   // stride 5: conflict-free
      #pragma unroll
      for (int k = 0; k < 7; ++k) orw[448 + i*7 + k] = o3[k];   // stride 7: conflict-free
    }
  }

  // ---- P2b: class-B jobs on waves 0-1 (8 rows x 16 ch = 128 jobs) ----
  if (t < 128){
    const int rowL = t >> 4;          // 0..7
    const int i    = 32 + (t & 15);   // 32..47
    if (row0 + rowL < n){
      const float* xr = xs + rowL * 368;
      float*     orw  = os + rowL * 672;
      float s = xr[i];
      float p[3];
      #pragma unroll
      for (int k = 0; k < 3; ++k) p[k] = xr[64 + i*3 + k];

      float o0 = 0.f;
      float o1[3] = {0.f,0.f,0.f};
      float o2[5] = {0.f,0.f,0.f,0.f,0.f};

      tp_path<0,0,0>(&s,&s, 0.5f*mix[  0+i], &o0);
      tp_path<0,1,1>(&s, p, 0.5f*mix[ 64+i],  o1);
      tp_path<1,0,1>( p,&s, 0.5f*mix[144+i],  o1);
      tp_path<1,1,0>( p, p, 0.5f*mix[192+i], &o0);
      tp_path<1,1,1>( p, p, 0.5f*mix[240+i],  o1);
      tp_path<1,1,2>( p, p, 0.5f*mix[288+i],  o2);

      o0 += keep[i] * s;
      const float k1 = keep[64+i];
      #pragma unroll
      for (int k = 0; k < 3; ++k) o1[k] += k1 * p[k];

      orw[i] = o0;
      #pragma unroll
      for (int k = 0; k < 3; ++k) orw[ 64 + i*3 + k] = o1[k];
      #pragma unroll
      for (int k = 0; k < 5; ++k) orw[208 + i*5 + k] = o2[k];
    }
  } else {
    // ---- P2c: class-C jobs on waves 2-3 (8 rows x 16 ch = 128 jobs) ----
    const int t2   = t - 128;
    const int rowL = t2 >> 4;         // 0..7
    const int i    = 48 + (t2 & 15);  // 48..63
    if (row0 + rowL < n){
      const float s = xs[rowL*368 + i];
      float o0 = 0.f;
      tp_path<0,0,0>(&s,&s, 0.5f*mix[0+i], &o0);
      o0 += keep[i] * s;
      os[rowL*672 + i] = o0;
    }
  }
  __syncthreads();

  // ---- P3: LDS -> global, 8 complete rows = 1344 f4, fully contiguous ----
  {
    const long long nf4o = (long long)n * 168;
    const long long base = row0 * 168;
    const float4* os4 = (const float4*)os;
    float4* __restrict__ o4 = (float4*)out;
    #pragma unroll
    for (int rnd = 0; rnd < 5; ++rnd){
      const int sidx = rnd*256 + t;           // 0..1279
      if (base + sidx < nf4o) o4[base + sidx] = os4[sidx];
    }
    const int sidx = 5*256 + t;               // 1280..1343 valid for t<64
    if (t < 64 && base + sidx < nf4o) o4[base + sidx] = os4[sidx];
  }
}

extern "C" void kernel_launch(void* const* d_in, const int* in_sizes, int n_in,
                              void* d_out, int out_size, void* d_ws, size_t ws_size,
                              hipStream_t stream)
{
  const float* x    = (const float*)d_in[0];
  const float* keep = (const float*)d_in[1];
  const float* mix  = (const float*)d_in[2];
  float* out = (float*)d_out;
  const int n = in_sizes[0] / 368;            // 32768
  const int blocks = (n + RPB - 1) / RPB;     // 4096
  selfmix_kernel<<<blocks, 256, 0, stream>>>(x, keep, mix, out, n);
}